// Round 4
// baseline (206.856 us; speedup 1.0000x reference)
//
#include <hip/hip_runtime.h>
#include <hip/hip_bf16.h>
#include <math.h>

typedef __attribute__((ext_vector_type(8))) short short8v;
typedef __attribute__((ext_vector_type(4))) float f32x4;

#define NB 64
#define CC 64
#define TT 300
#define VV 25
#define SS 3
#define TB 4
#define TBLK (TT/TB)    // 75
#define COLSF (TB*VV)   // 100

// ws float layout:
//   [o*16]            channel sum   (line-spread, 64 ch, stride 16 floats) [0..1024)
//   [1024 + o*16]     channel sumsq                                        [1024..2048)
//   [2048+o] scale, [2112+o] shift, [2176+o] summed bias
//   byte 16384: A-hat fragments [s][nt][lane] short8 (6*64*16 = 6144 B)
//   byte 65536: optional unnormalized-y bf16 buffer (NB*CC*TT*VV*2 = 61.44 MB)
#define YOFF_BYTES 65536

static __device__ __forceinline__ short f2bf(float f){
    union { __hip_bfloat16 h; short s; } u;
    u.h = __float2bfloat16(f);
    return u.s;
}
static __device__ __forceinline__ float bf2f(unsigned short b){
    return __uint_as_float(((unsigned)b) << 16);
}

__global__ void gcn_prep(const float* __restrict__ PA, const float* __restrict__ bc,
                         float* __restrict__ ws)
{
    __shared__ float inv[SS][VV];
    const int tid = threadIdx.x;   // 384 threads
    for (int i = tid; i < 2048; i += 384) ws[i] = 0.f;   // zero stats region
    if (tid < SS*VV){
        int s = tid/VV, w = tid%VV;
        float sum = 0.f;
        for (int v=0; v<VV; ++v){ float p = PA[s*VV*VV + v*VV + w]; sum = fmaf(p,p,sum); }
        inv[s][w] = 1.f/(sqrtf(sum)+1e-4f);
    }
    if (tid < CC) ws[2176 + tid] = bc[tid] + bc[CC+tid] + bc[2*CC+tid];
    __syncthreads();
    {   // fragment-ready normalized adjacency, zeros for v>=25 / w>=25
        int s = tid/128, rem = tid%128, nt = rem/64, lane = rem%64;
        int w = nt*16 + (lane&15), g = lane>>4;
        short8v vals;
        #pragma unroll
        for (int j=0;j<8;++j){
            int v = 8*g + j;
            float f = (v<VV && w<VV) ? PA[s*VV*VV + v*VV + w]*inv[s][w] : 0.f;
            vals[j] = f2bf(f);
        }
        *(short8v*)((char*)ws + 16384 + (size_t)((s*2+nt)*64 + lane)*16) = vals;
    }
}

template<bool YB>
__global__ __launch_bounds__(256,3) void gcn_main_kernel(
    const float* __restrict__ x, const float* __restrict__ Wc,
    float* __restrict__ ws, float* __restrict__ yf32,
    __hip_bfloat16* __restrict__ ybf)
{
    __shared__ unsigned short xs[256][40];      // rows=(c*4+t), bf16, v padded to 40
    __shared__ unsigned short zsT[2][112][68];  // dbuf: rows=(t*25+w), cols=c (pad 68)

    const int tid = threadIdx.x;
    const int wv  = tid >> 6, lane = tid & 63;
    const int l15 = lane & 15, g = lane >> 4;
    const int n   = blockIdx.x / TBLK;
    const int t0  = (blockIdx.x % TBLK) * TB;

    // zero junk K-columns 25..31 (avoid NaN*0 in stage-A MFMA)
    xs[tid][25] = 0;
    *(unsigned*)&xs[tid][26] = 0u;
    *(uint2*)&xs[tid][28] = make_uint2(0u,0u);

    // stage x tile -> xs bf16 (coalesced float4 loads, b16 scatter writes)
    const float4* x4 = (const float4*)(x + (size_t)n*(CC*TT*VV) + (size_t)t0*VV);
    for (int i4 = tid; i4 < CC*COLSF/4; i4 += 256){    // 1600 float4
        int c = i4 / (COLSF/4);
        int j = i4 % (COLSF/4);
        float4 v4 = x4[c*(TT*VV/4) + j];
        float vals[4] = {v4.x, v4.y, v4.z, v4.w};
        int e = 4*j;
        #pragma unroll
        for (int k=0;k<4;++k){
            int ee = e+k;
            xs[c*TB + ee/VV][ee%VV] = (unsigned short)f2bf(vals[k]);
        }
    }

    // hoisted operand fragments (global loads overlap the staging above;
    // one-time cost, keeps the s-loop free of vmcnt-drain serialization)
    short8v afA[SS][2];
    const short8v* wsfrag = (const short8v*)((const char*)ws + 16384);
    #pragma unroll
    for (int s=0;s<SS;++s)
        #pragma unroll
        for (int nt=0;nt<2;++nt)
            afA[s][nt] = wsfrag[(s*2+nt)*64 + lane];

    short8v wcf[SS][2];
    #pragma unroll
    for (int s=0;s<SS;++s){
        const float* wp = Wc + ((size_t)s*CC + (16*wv + l15))*CC + 8*g;
        float4 a0 = *(const float4*)(wp);
        float4 a1 = *(const float4*)(wp+4);
        float4 b0 = *(const float4*)(wp+32);
        float4 b1 = *(const float4*)(wp+36);
        short8v t0v, t1v;
        t0v[0]=f2bf(a0.x); t0v[1]=f2bf(a0.y); t0v[2]=f2bf(a0.z); t0v[3]=f2bf(a0.w);
        t0v[4]=f2bf(a1.x); t0v[5]=f2bf(a1.y); t0v[6]=f2bf(a1.z); t0v[7]=f2bf(a1.w);
        t1v[0]=f2bf(b0.x); t1v[1]=f2bf(b0.y); t1v[2]=f2bf(b0.z); t1v[3]=f2bf(b0.w);
        t1v[4]=f2bf(b1.x); t1v[5]=f2bf(b1.y); t1v[6]=f2bf(b1.z); t1v[7]=f2bf(b1.w);
        wcf[s][0] = t0v; wcf[s][1] = t1v;
    }

    __syncthreads();

    // hoisted x A-fragments: wave owns xs rows [64*wv, 64*wv+64)
    short8v axf[4];
    #pragma unroll
    for (int mt=0; mt<4; ++mt)
        axf[mt] = *(const short8v*)&xs[64*wv + 16*mt + l15][8*g];

    const f32x4 zf = {0.f,0.f,0.f,0.f};
    f32x4 yacc[7];
    #pragma unroll
    for (int nt=0; nt<7; ++nt) yacc[nt] = zf;

    #pragma unroll
    for (int s=0; s<SS; ++s){
        unsigned short (*zb)[68] = zsT[s & 1];

        // stage A: Z = X * A_hat[s]; scatter per mt (za transient: 8 regs)
        #pragma unroll
        for (int mt=0;mt<4;++mt){
            f32x4 za0 = __builtin_amdgcn_mfma_f32_16x16x32_bf16(axf[mt], afA[s][0], zf, 0,0,0);
            f32x4 za1 = __builtin_amdgcn_mfma_f32_16x16x32_bf16(axf[mt], afA[s][1], zf, 0,0,0);
            const int c = 16*wv + 4*mt + g;
            #pragma unroll
            for (int r=0;r<4;++r)
                zb[r*VV + l15][c] = (unsigned short)f2bf(za0[r]);   // w=l15 < 25
            if (l15 + 16 < VV){
                #pragma unroll
                for (int r=0;r<4;++r)
                    zb[r*VV + 16 + l15][c] = (unsigned short)f2bf(za1[r]);
            }
        }
        __syncthreads();   // zb ready; prev-s stage B (other buffer) already done pre-barrier

        // stage B: yacc += Wc[s] * Z   (K = c = 64, 2 k-tiles)
        #pragma unroll
        for (int nt=0;nt<7;++nt){
            short8v bz0 = *(const short8v*)&zb[nt*16 + l15][8*g];
            yacc[nt] = __builtin_amdgcn_mfma_f32_16x16x32_bf16(wcf[s][0], bz0, yacc[nt], 0,0,0);
            short8v bz1 = *(const short8v*)&zb[nt*16 + l15][32 + 8*g];
            yacc[nt] = __builtin_amdgcn_mfma_f32_16x16x32_bf16(wcf[s][1], bz1, yacc[nt], 0,0,0);
        }
    }

    // epilogue: bias, store unnormalized y (bf16 or f32), channel stats
    const float* wsb = ws + 2176;
    float s1[4] = {0,0,0,0}, s2[4] = {0,0,0,0};
    #pragma unroll
    for (int nt=0; nt<7; ++nt){
        int col = nt*16 + l15;
        if (col < COLSF){
            int t = col/VV, w = col%VV;
            #pragma unroll
            for (int r=0;r<4;++r){
                int o = 16*wv + 4*g + r;
                float v = yacc[nt][r] + wsb[o];
                size_t idx = (((size_t)n*CC + o)*TT + t0 + t)*VV + w;
                if (YB) ybf[idx] = __float2bfloat16(v);
                else    yf32[idx] = v;
                s1[r] += v;
                s2[r] = fmaf(v,v,s2[r]);
            }
        }
    }
    #pragma unroll
    for (int st=1; st<16; st<<=1){
        #pragma unroll
        for (int r=0;r<4;++r){
            s1[r] += __shfl_xor(s1[r], st);
            s2[r] += __shfl_xor(s2[r], st);
        }
    }
    if (l15 == 0){
        float* stats = (float*)ws;
        #pragma unroll
        for (int r=0;r<4;++r){
            int o = 16*wv + 4*g + r;
            atomicAdd(&stats[o*16], s1[r]);
            atomicAdd(&stats[1024 + o*16], s2[r]);
        }
    }
}

__global__ void gcn_finalize_kernel(const float* __restrict__ gamma,
                                    const float* __restrict__ beta,
                                    float* __restrict__ ws)
{
    const int o = threadIdx.x;
    if (o < CC) {
        const float cnt = (float)(NB * TT * VV);   // 480000
        const float mean = ws[o*16] / cnt;
        const float var  = ws[1024 + o*16] / cnt - mean * mean;
        const float sc   = gamma[o] * rsqrtf(var + 1e-5f);
        ws[2048 + o] = sc;
        ws[2112 + o] = beta[o] - mean * sc;
    }
}

template<bool YB>
__global__ __launch_bounds__(256) void gcn_bn_relu_kernel(
    const float* __restrict__ x, float* __restrict__ out,
    const float* __restrict__ ws, const unsigned short* __restrict__ ybf)
{
    const int total4 = NB * CC * TT * VV / 4;   // 7,680,000
    const int per_c4 = TT * VV / 4;             // 1875
    for (int i = blockIdx.x * 256 + threadIdx.x; i < total4; i += gridDim.x * 256) {
        const int c = (i / per_c4) & (CC - 1);
        const float sc = ws[2048 + c];
        const float sh = ws[2112 + c];
        float4 yv;
        if (YB){
            uint2 yb = *(const uint2*)&ybf[4*i];
            yv.x = bf2f((unsigned short)(yb.x & 0xffff));
            yv.y = bf2f((unsigned short)(yb.x >> 16));
            yv.z = bf2f((unsigned short)(yb.y & 0xffff));
            yv.w = bf2f((unsigned short)(yb.y >> 16));
        } else {
            yv = reinterpret_cast<float4*>(out)[i];
        }
        float4 xv = reinterpret_cast<const float4*>(x)[i];
        float4 r;
        r.x = fmaxf(fmaf(yv.x, sc, sh) + xv.x, 0.f);
        r.y = fmaxf(fmaf(yv.y, sc, sh) + xv.y, 0.f);
        r.z = fmaxf(fmaf(yv.z, sc, sh) + xv.z, 0.f);
        r.w = fmaxf(fmaf(yv.w, sc, sh) + xv.w, 0.f);
        reinterpret_cast<float4*>(out)[i] = r;
    }
}

extern "C" void kernel_launch(void* const* d_in, const int* in_sizes, int n_in,
                              void* d_out, int out_size, void* d_ws, size_t ws_size,
                              hipStream_t stream)
{
    const float* x     = (const float*)d_in[0];
    const float* PA    = (const float*)d_in[1];
    const float* Wc    = (const float*)d_in[2];
    const float* bc    = (const float*)d_in[3];
    const float* gamma = (const float*)d_in[4];
    const float* beta  = (const float*)d_in[5];
    float* out = (float*)d_out;
    float* ws  = (float*)d_ws;

    const size_t ybytes = (size_t)NB*CC*TT*VV*2;
    const bool yb = ws_size >= (size_t)YOFF_BYTES + ybytes;
    __hip_bfloat16* ybf = (__hip_bfloat16*)((char*)d_ws + YOFF_BYTES);

    gcn_prep<<<1, 384, 0, stream>>>(PA, bc, ws);
    if (yb){
        gcn_main_kernel<true><<<NB * TBLK, 256, 0, stream>>>(x, Wc, ws, out, ybf);
        gcn_finalize_kernel<<<1, 64, 0, stream>>>(gamma, beta, ws);
        gcn_bn_relu_kernel<true><<<2048, 256, 0, stream>>>(x, out, ws, (const unsigned short*)ybf);
    } else {
        gcn_main_kernel<false><<<NB * TBLK, 256, 0, stream>>>(x, Wc, ws, out, ybf);
        gcn_finalize_kernel<<<1, 64, 0, stream>>>(gamma, beta, ws);
        gcn_bn_relu_kernel<false><<<2048, 256, 0, stream>>>(x, out, ws, (const unsigned short*)ybf);
    }
}

// Round 5
// 192.705 us; speedup vs baseline: 1.0734x; 1.0734x over previous
//
#include <hip/hip_runtime.h>
#include <hip/hip_bf16.h>
#include <math.h>

typedef __attribute__((ext_vector_type(8))) short short8v;
typedef __attribute__((ext_vector_type(4))) float f32x4;

#define NB 64
#define CC 64
#define TT 300
#define VV 25
#define SS 3
#define TB 4
#define TBLK (TT/TB)    // 75
#define COLSF (TB*VV)   // 100

// ws float layout:
//   [(n*64+o)*8]      per-n channel sum      [0 .. 32768)   (128 KB)
//   [(n*64+o)*8+4]    per-n channel sumsq
//   [32768+o] scale, [32832+o] shift, [32896+o] summed bias
//   byte 163840: A-hat fragments [s][nt][lane] short8 (6*64*16 = 6144 B)
//   byte 262144: unnormalized-y bf16 buffer (NB*CC*TT*VV*2 = 61.44 MB)
#define FRAG_BYTES 163840
#define YOFF_BYTES 262144

static __device__ __forceinline__ short f2bf(float f){
    union { __hip_bfloat16 h; short s; } u;
    u.h = __float2bfloat16(f);
    return u.s;
}
static __device__ __forceinline__ float bf2f(unsigned short b){
    return __uint_as_float(((unsigned)b) << 16);
}

__global__ void gcn_prep(const float* __restrict__ PA, const float* __restrict__ bc,
                         float* __restrict__ ws)
{
    __shared__ float inv[SS][VV];
    const int tid = threadIdx.x;   // 384 threads
    for (int i = tid; i < 32768; i += 384) ws[i] = 0.f;   // zero per-n partials
    if (tid < SS*VV){
        int s = tid/VV, w = tid%VV;
        float sum = 0.f;
        for (int v=0; v<VV; ++v){ float p = PA[s*VV*VV + v*VV + w]; sum = fmaf(p,p,sum); }
        inv[s][w] = 1.f/(sqrtf(sum)+1e-4f);
    }
    if (tid < CC) ws[32896 + tid] = bc[tid] + bc[CC+tid] + bc[2*CC+tid];
    __syncthreads();
    {   // fragment-ready normalized adjacency, zeros for v>=25 / w>=25
        int s = tid/128, rem = tid%128, nt = rem/64, lane = rem%64;
        int w = nt*16 + (lane&15), g = lane>>4;
        short8v vals;
        #pragma unroll
        for (int j=0;j<8;++j){
            int v = 8*g + j;
            float f = (v<VV && w<VV) ? PA[s*VV*VV + v*VV + w]*inv[s][w] : 0.f;
            vals[j] = f2bf(f);
        }
        *(short8v*)((char*)ws + FRAG_BYTES + (size_t)((s*2+nt)*64 + lane)*16) = vals;
    }
}

template<bool YB>
__global__ __launch_bounds__(256,4) void gcn_main_kernel(
    const float* __restrict__ x, const float* __restrict__ Wc,
    float* __restrict__ ws, float* __restrict__ yf32,
    __hip_bfloat16* __restrict__ ybf)
{
    __shared__ unsigned short zsT[2][112][68];  // 30464 B — only LDS in the kernel

    const int tid = threadIdx.x;
    const int wv  = tid >> 6, lane = tid & 63;
    const int l15 = lane & 15, g = lane >> 4;
    const int n   = blockIdx.x / TBLK;
    const int t0  = (blockIdx.x % TBLK) * TB;

    // stage-A x fragments loaded DIRECTLY from global (no LDS round-trip):
    // lane (l15,g) of wave wv, tile mt covers row = 64wv+16mt+l15 = (c*4+t),
    // k-elements v = 8g..8g+7 (v>=25 zero-padded; only v=24 valid for g=3)
    short8v axf[4];
    #pragma unroll
    for (int mt=0; mt<4; ++mt){
        const int row = 64*wv + 16*mt + l15;
        const int c = row >> 2, t = row & 3;
        const float* p = x + ((size_t)(n*CC + c)*TT + (t0 + t))*VV + 8*g;
        short8v f;
        if (g < 3){
            float4 a = *(const float4*)p;
            float4 b = *(const float4*)(p+4);
            f[0]=f2bf(a.x); f[1]=f2bf(a.y); f[2]=f2bf(a.z); f[3]=f2bf(a.w);
            f[4]=f2bf(b.x); f[5]=f2bf(b.y); f[6]=f2bf(b.z); f[7]=f2bf(b.w);
        } else {
            f[0]=f2bf(p[0]);                 // v=24
            f[1]=0; f[2]=0; f[3]=0; f[4]=0; f[5]=0; f[6]=0; f[7]=0;
        }
        axf[mt] = f;
    }

    const f32x4 zf = {0.f,0.f,0.f,0.f};
    f32x4 yacc[7];
    #pragma unroll
    for (int nt=0; nt<7; ++nt) yacc[nt] = zf;

    const short8v* wsfrag = (const short8v*)((const char*)ws + FRAG_BYTES);

    #pragma unroll 1
    for (int s=0; s<SS; ++s){
        unsigned short (*zb)[68] = zsT[s & 1];

        // per-s operand fragments (L2-hot; overlap with stage-A MFMAs below)
        short8v afA0 = wsfrag[(s*2+0)*64 + lane];
        short8v afA1 = wsfrag[(s*2+1)*64 + lane];
        short8v wcf0, wcf1;
        {
            const float* wp = Wc + ((size_t)s*CC + (16*wv + l15))*CC + 8*g;
            float4 a0 = *(const float4*)(wp);
            float4 a1 = *(const float4*)(wp+4);
            float4 b0 = *(const float4*)(wp+32);
            float4 b1 = *(const float4*)(wp+36);
            wcf0[0]=f2bf(a0.x); wcf0[1]=f2bf(a0.y); wcf0[2]=f2bf(a0.z); wcf0[3]=f2bf(a0.w);
            wcf0[4]=f2bf(a1.x); wcf0[5]=f2bf(a1.y); wcf0[6]=f2bf(a1.z); wcf0[7]=f2bf(a1.w);
            wcf1[0]=f2bf(b0.x); wcf1[1]=f2bf(b0.y); wcf1[2]=f2bf(b0.z); wcf1[3]=f2bf(b0.w);
            wcf1[4]=f2bf(b1.x); wcf1[5]=f2bf(b1.y); wcf1[6]=f2bf(b1.z); wcf1[7]=f2bf(b1.w);
        }

        // stage A: Z = X * A_hat[s]; scatter per mt (za transient: 8 regs)
        #pragma unroll
        for (int mt=0;mt<4;++mt){
            f32x4 za0 = __builtin_amdgcn_mfma_f32_16x16x32_bf16(axf[mt], afA0, zf, 0,0,0);
            f32x4 za1 = __builtin_amdgcn_mfma_f32_16x16x32_bf16(axf[mt], afA1, zf, 0,0,0);
            const int c = 16*wv + 4*mt + g;
            #pragma unroll
            for (int r=0;r<4;++r)
                zb[r*VV + l15][c] = (unsigned short)f2bf(za0[r]);   // w=l15 < 25
            if (l15 + 16 < VV){
                #pragma unroll
                for (int r=0;r<4;++r)
                    zb[r*VV + 16 + l15][c] = (unsigned short)f2bf(za1[r]);
            }
        }
        // one barrier per s: writes to zb visible; also separates next-s writes
        // from this-s reads (next-s write happens after next barrier in program order)
        __syncthreads();

        // stage B: yacc += Wc[s] * Z   (K = c = 64, 2 k-tiles)
        #pragma unroll
        for (int nt=0;nt<7;++nt){
            short8v bz0 = *(const short8v*)&zb[nt*16 + l15][8*g];
            yacc[nt] = __builtin_amdgcn_mfma_f32_16x16x32_bf16(wcf0, bz0, yacc[nt], 0,0,0);
            short8v bz1 = *(const short8v*)&zb[nt*16 + l15][32 + 8*g];
            yacc[nt] = __builtin_amdgcn_mfma_f32_16x16x32_bf16(wcf1, bz1, yacc[nt], 0,0,0);
        }
    }

    // epilogue: bias, store unnormalized y (bf16 or f32), per-n channel stats
    const float* wsb = ws + 32896;
    float s1[4] = {0,0,0,0}, s2[4] = {0,0,0,0};
    #pragma unroll
    for (int nt=0; nt<7; ++nt){
        int col = nt*16 + l15;
        if (col < COLSF){
            int t = col/VV, w = col%VV;
            #pragma unroll
            for (int r=0;r<4;++r){
                int o = 16*wv + 4*g + r;
                float v = yacc[nt][r] + wsb[o];
                size_t idx = (((size_t)n*CC + o)*TT + t0 + t)*VV + w;
                if (YB) ybf[idx] = __float2bfloat16(v);
                else    yf32[idx] = v;
                s1[r] += v;
                s2[r] = fmaf(v,v,s2[r]);
            }
        }
    }
    #pragma unroll
    for (int st=1; st<16; st<<=1){
        #pragma unroll
        for (int r=0;r<4;++r){
            s1[r] += __shfl_xor(s1[r], st);
            s2[r] += __shfl_xor(s2[r], st);
        }
    }
    if (l15 == 0){
        float* ps = ws + (size_t)n*64*8;
        #pragma unroll
        for (int r=0;r<4;++r){
            int o = 16*wv + 4*g + r;
            atomicAdd(&ps[o*8],     s1[r]);
            atomicAdd(&ps[o*8 + 4], s2[r]);
        }
    }
}

__global__ void gcn_finalize_kernel(const float* __restrict__ gamma,
                                    const float* __restrict__ beta,
                                    float* __restrict__ ws)
{
    const int o = threadIdx.x;
    if (o < CC) {
        float s = 0.f, q = 0.f;
        for (int n = 0; n < NB; ++n){
            s += ws[(n*64 + o)*8];
            q += ws[(n*64 + o)*8 + 4];
        }
        const float cnt = (float)(NB * TT * VV);   // 480000
        const float mean = s / cnt;
        const float var  = q / cnt - mean * mean;
        const float sc   = gamma[o] * rsqrtf(var + 1e-5f);
        ws[32768 + o] = sc;
        ws[32832 + o] = beta[o] - mean * sc;
    }
}

template<bool YB>
__global__ __launch_bounds__(256) void gcn_bn_relu_kernel(
    const float* __restrict__ x, float* __restrict__ out,
    const float* __restrict__ ws, const unsigned short* __restrict__ ybf)
{
    const int total4 = NB * CC * TT * VV / 4;   // 7,680,000
    const int per_c4 = TT * VV / 4;             // 1875
    for (int i = blockIdx.x * 256 + threadIdx.x; i < total4; i += gridDim.x * 256) {
        const int c = (i / per_c4) & (CC - 1);
        const float sc = ws[32768 + c];
        const float sh = ws[32832 + c];
        float4 yv;
        if (YB){
            uint2 yb = *(const uint2*)&ybf[4*i];
            yv.x = bf2f((unsigned short)(yb.x & 0xffff));
            yv.y = bf2f((unsigned short)(yb.x >> 16));
            yv.z = bf2f((unsigned short)(yb.y & 0xffff));
            yv.w = bf2f((unsigned short)(yb.y >> 16));
        } else {
            yv = reinterpret_cast<float4*>(out)[i];
        }
        float4 xv = reinterpret_cast<const float4*>(x)[i];
        float4 r;
        r.x = fmaxf(fmaf(yv.x, sc, sh) + xv.x, 0.f);
        r.y = fmaxf(fmaf(yv.y, sc, sh) + xv.y, 0.f);
        r.z = fmaxf(fmaf(yv.z, sc, sh) + xv.z, 0.f);
        r.w = fmaxf(fmaf(yv.w, sc, sh) + xv.w, 0.f);
        reinterpret_cast<float4*>(out)[i] = r;
    }
}

extern "C" void kernel_launch(void* const* d_in, const int* in_sizes, int n_in,
                              void* d_out, int out_size, void* d_ws, size_t ws_size,
                              hipStream_t stream)
{
    const float* x     = (const float*)d_in[0];
    const float* PA    = (const float*)d_in[1];
    const float* Wc    = (const float*)d_in[2];
    const float* bc    = (const float*)d_in[3];
    const float* gamma = (const float*)d_in[4];
    const float* beta  = (const float*)d_in[5];
    float* out = (float*)d_out;
    float* ws  = (float*)d_ws;

    const size_t ybytes = (size_t)NB*CC*TT*VV*2;
    const bool yb = ws_size >= (size_t)YOFF_BYTES + ybytes;
    __hip_bfloat16* ybf = (__hip_bfloat16*)((char*)d_ws + YOFF_BYTES);

    gcn_prep<<<1, 384, 0, stream>>>(PA, bc, ws);
    if (yb){
        gcn_main_kernel<true><<<NB * TBLK, 256, 0, stream>>>(x, Wc, ws, out, ybf);
        gcn_finalize_kernel<<<1, 64, 0, stream>>>(gamma, beta, ws);
        gcn_bn_relu_kernel<true><<<2048, 256, 0, stream>>>(x, out, ws, (const unsigned short*)ybf);
    } else {
        gcn_main_kernel<false><<<NB * TBLK, 256, 0, stream>>>(x, Wc, ws, out, ybf);
        gcn_finalize_kernel<<<1, 64, 0, stream>>>(gamma, beta, ws);
        gcn_bn_relu_kernel<false><<<2048, 256, 0, stream>>>(x, out, ws, (const unsigned short*)ybf);
    }
}

// Round 6
// 131.682 us; speedup vs baseline: 1.5709x; 1.4634x over previous
//
#include <hip/hip_runtime.h>
#include <hip/hip_bf16.h>
#include <math.h>

typedef __attribute__((ext_vector_type(8))) short short8v;
typedef __attribute__((ext_vector_type(4))) float f32x4;

#define NB 64
#define CC 64
#define TT 300
#define VV 25
#define SS 3

// ws layout (floats unless noted):
//   [o*8] channel sum, [o*8+4] channel sumsq      (line-spread, zeroed by prep)
//   [1024+o] scale, [1088+o] shift
//   byte 16384: A-hat frags  [s][nt][lane] 16B    (6*64*16   = 6144 B)
//   byte 32768: Wc bf16 frags [s][ot][kt][lane]   (24*64*16  = 24576 B)
//   byte 65536: unnormalized-y bf16 buffer        (64*64*300*25*2 = 61.44 MB)
#define AFA_BYTES 16384
#define WCF_BYTES 32768
#define YOFF_BYTES 65536

static __device__ __forceinline__ unsigned short f2bf(float f){
    union { __hip_bfloat16 h; unsigned short s; } u;
    u.h = __float2bfloat16(f);
    return u.s;
}
static __device__ __forceinline__ float bf2f(unsigned short b){
    return __uint_as_float(((unsigned)b) << 16);
}
static __device__ __forceinline__ void pack2(const f32x4& z, unsigned& d0, unsigned& d1){
    d0 = (unsigned)f2bf(z[0]) | ((unsigned)f2bf(z[1]) << 16);
    d1 = (unsigned)f2bf(z[2]) | ((unsigned)f2bf(z[3]) << 16);
}
static __device__ __forceinline__ short8v mk8(unsigned q0,unsigned q1,unsigned q2,unsigned q3){
    union { unsigned u[4]; short8v v; } x;
    x.u[0]=q0; x.u[1]=q1; x.u[2]=q2; x.u[3]=q3;
    return x.v;
}

__global__ void gcn_prep(const float* __restrict__ PA, const float* __restrict__ Wc,
                         float* __restrict__ ws)
{
    __shared__ float inv[SS][VV];
    const int tid = threadIdx.x;   // 384 threads
    for (int i = tid; i < 1152; i += 384) if (i < 512 || i >= 1024) ws[i] = 0.f;
    if (tid < SS*VV){
        int s = tid/VV, w = tid%VV;
        float sum = 0.f;
        for (int v=0; v<VV; ++v){ float p = PA[s*VV*VV + v*VV + w]; sum = fmaf(p,p,sum); }
        inv[s][w] = 1.f/(sqrtf(sum)+1e-4f);
    }
    __syncthreads();
    {   // A-hat fragments (stage-A B operand), zeros for v>=25 / w>=25
        int s = tid/128, rem = tid%128, nt = rem/64, lane = rem%64;
        int w = nt*16 + (lane&15), g = lane>>4;
        short8v vals;
        #pragma unroll
        for (int j=0;j<8;++j){
            int v = 8*g + j;
            float f = (v<VV && w<VV) ? PA[s*VV*VV + v*VV + w]*inv[s][w] : 0.f;
            vals[j] = (short)f2bf(f);
        }
        *(short8v*)((char*)ws + AFA_BYTES + (size_t)((s*2+nt)*64 + lane)*16) = vals;
    }
    // Wc fragments (stage-B A operand): fid = ((s*4+ot)*2+kt)*64+lane
    for (int fid = tid; fid < SS*4*2*64; fid += 384){
        int lane = fid & 63;
        int kt = (fid >> 6) & 1;
        int ot = (fid >> 7) & 3;
        int s  = fid >> 9;
        int o  = 16*ot + (lane & 15);
        int c0 = kt*32 + 8*(lane >> 4);
        short8v vals;
        #pragma unroll
        for (int j=0;j<8;++j) vals[j] = (short)f2bf(Wc[((size_t)s*CC + o)*CC + c0 + j]);
        *(short8v*)((char*)ws + WCF_BYTES + (size_t)fid*16) = vals;
    }
}

template<bool YB>
__global__ __launch_bounds__(256,4) void gcn_main_kernel(
    const float* __restrict__ x, const float* __restrict__ ws,
    float* __restrict__ yf32, __hip_bfloat16* __restrict__ ybf)
{
    const int lane = threadIdx.x & 63;
    const int wv   = threadIdx.x >> 6;
    const int l15  = lane & 15, g = lane >> 4;
    const int gid  = blockIdx.x * 4 + wv;    // 0..19199 = (n,t)
    const int n    = gid / TT;
    const int t    = gid % TT;

    // stage-A x fragments direct from global: rows c = 16*mt+l15 (fixed t), k = v
    short8v axf[4];
    #pragma unroll
    for (int mt=0; mt<4; ++mt){
        const int c = 16*mt + l15;
        const float* p = x + ((size_t)(n*CC + c)*TT + t)*VV + 8*g;
        short8v f;
        if (g < 3){
            float4 a = *(const float4*)p;
            float4 b = *(const float4*)(p+4);
            f[0]=(short)f2bf(a.x); f[1]=(short)f2bf(a.y); f[2]=(short)f2bf(a.z); f[3]=(short)f2bf(a.w);
            f[4]=(short)f2bf(b.x); f[5]=(short)f2bf(b.y); f[6]=(short)f2bf(b.z); f[7]=(short)f2bf(b.w);
        } else {
            f[0]=(short)f2bf(p[0]);   // v=24
            f[1]=0; f[2]=0; f[3]=0; f[4]=0; f[5]=0; f[6]=0; f[7]=0;
        }
        axf[mt] = f;
    }

    const short8v* afrag = (const short8v*)((const char*)ws + AFA_BYTES);
    const short8v* wfrag = (const short8v*)((const char*)ws + WCF_BYTES);

    const f32x4 zf = {0.f,0.f,0.f,0.f};
    f32x4 yacc[4][2];
    #pragma unroll
    for (int ot=0; ot<4; ++ot){ yacc[ot][0]=zf; yacc[ot][1]=zf; }

    const int sLo = 32*(g&1) + l15;
    const int sHi = sLo + 16;
    const bool hi = (lane >= 32);

    #pragma unroll 1
    for (int s=0; s<SS; ++s){
        short8v aA0 = afrag[(s*2+0)*64 + lane];
        short8v aA1 = afrag[(s*2+1)*64 + lane];
        #pragma unroll
        for (int kt=0; kt<2; ++kt){
            // stage A: Z rows c in [kt*32, kt*32+32)
            f32x4 z00 = __builtin_amdgcn_mfma_f32_16x16x32_bf16(axf[2*kt+0], aA0, zf, 0,0,0);
            f32x4 z01 = __builtin_amdgcn_mfma_f32_16x16x32_bf16(axf[2*kt+0], aA1, zf, 0,0,0);
            f32x4 z10 = __builtin_amdgcn_mfma_f32_16x16x32_bf16(axf[2*kt+1], aA0, zf, 0,0,0);
            f32x4 z11 = __builtin_amdgcn_mfma_f32_16x16x32_bf16(axf[2*kt+1], aA1, zf, 0,0,0);
            unsigned pLo0n0, pLo1n0, pLo0n1, pLo1n1;   // mt = 2kt   : [nt][d]
            unsigned pHi0n0, pHi1n0, pHi0n1, pHi1n1;   // mt = 2kt+1
            pack2(z00, pLo0n0, pLo1n0);
            pack2(z01, pLo0n1, pLo1n1);
            pack2(z10, pHi0n0, pHi1n0);
            pack2(z11, pHi0n1, pHi1n1);
            // in-register transpose -> stage-B B-fragments (k = c octets)
            unsigned a0,b0,a1,b1,a2,b2,a3,b3;
            a0=__shfl(pLo0n0,sLo); b0=__shfl(pHi0n0,sLo);
            a1=__shfl(pLo1n0,sLo); b1=__shfl(pHi1n0,sLo);
            a2=__shfl(pLo0n0,sHi); b2=__shfl(pHi0n0,sHi);
            a3=__shfl(pLo1n0,sHi); b3=__shfl(pHi1n0,sHi);
            short8v bz0 = mk8(hi?b0:a0, hi?b1:a1, hi?b2:a2, hi?b3:a3);
            a0=__shfl(pLo0n1,sLo); b0=__shfl(pHi0n1,sLo);
            a1=__shfl(pLo1n1,sLo); b1=__shfl(pHi1n1,sLo);
            a2=__shfl(pLo0n1,sHi); b2=__shfl(pHi0n1,sHi);
            a3=__shfl(pLo1n1,sHi); b3=__shfl(pHi1n1,sHi);
            short8v bz1 = mk8(hi?b0:a0, hi?b1:a1, hi?b2:a2, hi?b3:a3);
            // stage B: 4 o-tiles x 2 nt, this kt
            #pragma unroll
            for (int ot=0; ot<4; ++ot){
                short8v wc = wfrag[((s*4+ot)*2+kt)*64 + lane];
                yacc[ot][0] = __builtin_amdgcn_mfma_f32_16x16x32_bf16(wc, bz0, yacc[ot][0], 0,0,0);
                yacc[ot][1] = __builtin_amdgcn_mfma_f32_16x16x32_bf16(wc, bz1, yacc[ot][1], 0,0,0);
            }
        }
    }

    // store unnormalized y (bias cancels through training-mode BN — omitted)
    #pragma unroll
    for (int ot=0; ot<4; ++ot){
        #pragma unroll
        for (int r=0; r<4; ++r){
            const int o = 16*ot + 4*g + r;
            const size_t base = (size_t)(n*CC + o)*(TT*VV) + (size_t)t*VV;
            if (YB){
                ybf[base + l15] = __float2bfloat16(yacc[ot][0][r]);
                if (l15 < VV-16) ybf[base + 16 + l15] = __float2bfloat16(yacc[ot][1][r]);
            } else {
                yf32[base + l15] = yacc[ot][0][r];
                if (l15 < VV-16) yf32[base + 16 + l15] = yacc[ot][1][r];
            }
        }
    }
}

template<bool YB>
__global__ __launch_bounds__(256) void gcn_stat_kernel(
    const float* __restrict__ yf, const unsigned short* __restrict__ ybf,
    float* __restrict__ ws)
{
    __shared__ float red[2][4];
    const int b = blockIdx.x;           // n*64 + o  (4096 blocks)
    float s1 = 0.f, s2 = 0.f;
    if (YB){
        const uint2* p = (const uint2*)(ybf + (size_t)b*(TT*VV));
        for (int i = threadIdx.x; i < TT*VV/4; i += 256){
            uint2 u = p[i];
            float a0=bf2f((unsigned short)(u.x&0xffff)), a1=bf2f((unsigned short)(u.x>>16));
            float a2=bf2f((unsigned short)(u.y&0xffff)), a3=bf2f((unsigned short)(u.y>>16));
            s1 += (a0+a1)+(a2+a3);
            s2 = fmaf(a0,a0,fmaf(a1,a1,fmaf(a2,a2,fmaf(a3,a3,s2))));
        }
    } else {
        const float4* p = (const float4*)(yf + (size_t)b*(TT*VV));
        for (int i = threadIdx.x; i < TT*VV/4; i += 256){
            float4 v = p[i];
            s1 += (v.x+v.y)+(v.z+v.w);
            s2 = fmaf(v.x,v.x,fmaf(v.y,v.y,fmaf(v.z,v.z,fmaf(v.w,v.w,s2))));
        }
    }
    #pragma unroll
    for (int m=1; m<64; m<<=1){ s1 += __shfl_xor(s1,m); s2 += __shfl_xor(s2,m); }
    const int wv = threadIdx.x >> 6;
    if ((threadIdx.x & 63) == 0){ red[0][wv]=s1; red[1][wv]=s2; }
    __syncthreads();
    if (threadIdx.x == 0){
        float S1 = red[0][0]+red[0][1]+red[0][2]+red[0][3];
        float S2 = red[1][0]+red[1][1]+red[1][2]+red[1][3];
        int o = b & (CC-1);
        atomicAdd(&ws[o*8],     S1);
        atomicAdd(&ws[o*8 + 4], S2);
    }
}

__global__ void gcn_finalize_kernel(const float* __restrict__ gamma,
                                    const float* __restrict__ beta,
                                    float* __restrict__ ws)
{
    const int o = threadIdx.x;
    if (o < CC) {
        const float cnt = (float)(NB * TT * VV);   // 480000
        const float mean = ws[o*8] / cnt;
        const float var  = ws[o*8 + 4] / cnt - mean * mean;
        const float sc   = gamma[o] * rsqrtf(var + 1e-5f);
        ws[1024 + o] = sc;
        ws[1088 + o] = beta[o] - mean * sc;
    }
}

template<bool YB>
__global__ __launch_bounds__(256) void gcn_bn_relu_kernel(
    const float* __restrict__ x, float* __restrict__ out,
    const float* __restrict__ ws, const unsigned short* __restrict__ ybf)
{
    const int total4 = NB * CC * TT * VV / 4;   // 7,680,000
    const int per_c4 = TT * VV / 4;             // 1875
    for (int i = blockIdx.x * 256 + threadIdx.x; i < total4; i += gridDim.x * 256) {
        const int c = (i / per_c4) & (CC - 1);
        const float sc = ws[1024 + c];
        const float sh = ws[1088 + c];
        float4 yv;
        if (YB){
            uint2 yb = *(const uint2*)&ybf[4*i];
            yv.x = bf2f((unsigned short)(yb.x & 0xffff));
            yv.y = bf2f((unsigned short)(yb.x >> 16));
            yv.z = bf2f((unsigned short)(yb.y & 0xffff));
            yv.w = bf2f((unsigned short)(yb.y >> 16));
        } else {
            yv = reinterpret_cast<float4*>(out)[i];
        }
        float4 xv = reinterpret_cast<const float4*>(x)[i];
        float4 r;
        r.x = fmaxf(fmaf(yv.x, sc, sh) + xv.x, 0.f);
        r.y = fmaxf(fmaf(yv.y, sc, sh) + xv.y, 0.f);
        r.z = fmaxf(fmaf(yv.z, sc, sh) + xv.z, 0.f);
        r.w = fmaxf(fmaf(yv.w, sc, sh) + xv.w, 0.f);
        reinterpret_cast<float4*>(out)[i] = r;
    }
}

extern "C" void kernel_launch(void* const* d_in, const int* in_sizes, int n_in,
                              void* d_out, int out_size, void* d_ws, size_t ws_size,
                              hipStream_t stream)
{
    const float* x     = (const float*)d_in[0];
    const float* PA    = (const float*)d_in[1];
    const float* Wc    = (const float*)d_in[2];
    const float* gamma = (const float*)d_in[4];
    const float* beta  = (const float*)d_in[5];
    float* out = (float*)d_out;
    float* ws  = (float*)d_ws;

    const size_t ybytes = (size_t)NB*CC*TT*VV*2;
    const bool yb = ws_size >= (size_t)YOFF_BYTES + ybytes;
    __hip_bfloat16* ybf = (__hip_bfloat16*)((char*)d_ws + YOFF_BYTES);

    gcn_prep<<<1, 384, 0, stream>>>(PA, Wc, ws);
    if (yb){
        gcn_main_kernel<true><<<NB*TT/4, 256, 0, stream>>>(x, ws, out, ybf);
        gcn_stat_kernel<true><<<NB*CC, 256, 0, stream>>>(out, (const unsigned short*)ybf, ws);
        gcn_finalize_kernel<<<1, 64, 0, stream>>>(gamma, beta, ws);
        gcn_bn_relu_kernel<true><<<2048, 256, 0, stream>>>(x, out, ws, (const unsigned short*)ybf);
    } else {
        gcn_main_kernel<false><<<NB*TT/4, 256, 0, stream>>>(x, ws, out, ybf);
        gcn_stat_kernel<false><<<NB*CC, 256, 0, stream>>>(out, (const unsigned short*)ybf, ws);
        gcn_finalize_kernel<<<1, 64, 0, stream>>>(gamma, beta, ws);
        gcn_bn_relu_kernel<false><<<2048, 256, 0, stream>>>(x, out, ws, (const unsigned short*)ybf);
    }
}